// Round 3
// baseline (230.170 us; speedup 1.0000x reference)
//
#include <hip/hip_runtime.h>
#include <math.h>

// Side-window filter, FP32, bit-exact vs the np reference (absmax==0.0):
// each directional conv is a sequential fp32 FMA chain over taps in row-major
// (ky,kx) order, acc starting at 0, weights fp32(1/15), fp32(1/9),
// fp32(fp32(1/9)/9). Zero-padded taps are exact no-ops.
//
// Round 9: 3-dispatch path with 64x64 tiles. Round 8's regression had two
// causes, both counter-visible: (a) __launch_bounds__(256,8) squeezed VGPRs
// 40->32 (AGPR shuffling of the 32 live accumulators, no load-prefetch
// distance; ops/px 133->159), (b) only 2 swf4 segments per barrier made
// staging+barrier a 45% serial fraction (VALUBusy 55%). Fix: 64x64 tile
// (LDS 68x68 = 18.5 KB, still 8 blocks/CU threads-limited, but 4 segments
// per thread per barrier), default launch_bounds(256) (round-1's 85%-busy
// register config), interior fast-path staging, pow2 segment indexing.
// VALU-issue floor for the 3 dispatches is ~86 us; target ~80% busy.
//
// Direction supports (with the reference's normalization bug):
//   d0 L  = rows[-2..2] x cols[-2..0] * (1/15)
//   d1 R  = rows[-2..2] x cols[0..2]  * (1/15)
//   d2 U  = rows[-2..0] x cols[-2..2] * (1/15)
//   d3 D  = rows[0..2]  x cols[-2..2] * (1/15)
//   d4 NW = rows[-2..0] x cols[-2..0] * (1/9)
//   d5 NE = NW support * (1/81)   (bug: NE = new NW / 9)
//   d6 SW = rows[0..2]  x cols[-2..0] * (1/9)
//   d7 SE = SW support * (1/81)   (bug: SE = new SW / 9)

typedef float f4v __attribute__((ext_vector_type(4)));
typedef float f2v __attribute__((ext_vector_type(2), aligned(8)));

// Core math for 4 horizontally-adjacent pixels. rp points at the (-2,-2) tap
// of pixel 0 in an LDS tile of pitch PW floats (rows 16B-aligned). The
// per-accumulator op order (rows ascending, cols ascending within row) is the
// verified bit-exact chain — do not reorder.
template<int PW>
__device__ __forceinline__ f4v swf4(const float* __restrict__ rp) {
    const float w15 = 1.0f / 15.0f;
    const float w9  = 1.0f / 9.0f;
    const float w81 = (1.0f / 9.0f) / 9.0f;

    float acc[8][4];
    #pragma unroll
    for (int d = 0; d < 8; d++)
        #pragma unroll
        for (int j = 0; j < 4; j++) acc[d][j] = 0.0f;
    float ctr[4];

    #pragma unroll
    for (int r = 0; r < 5; r++) {
        const float* p = rp + r * PW;     // 16B-aligned
        f4v lo = *(const f4v*)p;
        f4v hi = *(const f4v*)(p + 4);
        float w[8] = {lo.x, lo.y, lo.z, lo.w, hi.x, hi.y, hi.z, hi.w};

        #pragma unroll
        for (int j = 0; j < 4; j++) {
            // full-height: L (cols j..j+2), R (cols j+2..j+4)
            acc[0][j] = fmaf(w15, w[j + 0], acc[0][j]);
            acc[0][j] = fmaf(w15, w[j + 1], acc[0][j]);
            acc[0][j] = fmaf(w15, w[j + 2], acc[0][j]);
            acc[1][j] = fmaf(w15, w[j + 2], acc[1][j]);
            acc[1][j] = fmaf(w15, w[j + 3], acc[1][j]);
            acc[1][j] = fmaf(w15, w[j + 4], acc[1][j]);
            if (r < 3) {  // U, NW, NE
                acc[2][j] = fmaf(w15, w[j + 0], acc[2][j]);
                acc[2][j] = fmaf(w15, w[j + 1], acc[2][j]);
                acc[2][j] = fmaf(w15, w[j + 2], acc[2][j]);
                acc[2][j] = fmaf(w15, w[j + 3], acc[2][j]);
                acc[2][j] = fmaf(w15, w[j + 4], acc[2][j]);
                acc[4][j] = fmaf(w9,  w[j + 0], acc[4][j]);
                acc[4][j] = fmaf(w9,  w[j + 1], acc[4][j]);
                acc[4][j] = fmaf(w9,  w[j + 2], acc[4][j]);
                acc[5][j] = fmaf(w81, w[j + 0], acc[5][j]);
                acc[5][j] = fmaf(w81, w[j + 1], acc[5][j]);
                acc[5][j] = fmaf(w81, w[j + 2], acc[5][j]);
            }
            if (r >= 2) {  // D, SW, SE
                acc[3][j] = fmaf(w15, w[j + 0], acc[3][j]);
                acc[3][j] = fmaf(w15, w[j + 1], acc[3][j]);
                acc[3][j] = fmaf(w15, w[j + 2], acc[3][j]);
                acc[3][j] = fmaf(w15, w[j + 3], acc[3][j]);
                acc[3][j] = fmaf(w15, w[j + 4], acc[3][j]);
                acc[6][j] = fmaf(w9,  w[j + 0], acc[6][j]);
                acc[6][j] = fmaf(w9,  w[j + 1], acc[6][j]);
                acc[6][j] = fmaf(w9,  w[j + 2], acc[6][j]);
                acc[7][j] = fmaf(w81, w[j + 0], acc[7][j]);
                acc[7][j] = fmaf(w81, w[j + 1], acc[7][j]);
                acc[7][j] = fmaf(w81, w[j + 2], acc[7][j]);
            }
            if (r == 2) ctr[j] = w[j + 2];
        }
    }

    f4v R;
    #pragma unroll
    for (int j = 0; j < 4; j++) {
        const float c = ctr[j];
        const float e0 = acc[0][j] - c, e1 = acc[1][j] - c;
        const float e2 = acc[2][j] - c, e3 = acc[3][j] - c;
        const float e4 = acc[4][j] - c, e5 = acc[5][j] - c;
        const float e6 = acc[6][j] - c, e7 = acc[7][j] - c;
        // tournament argmin on |d|; strict < keeps lowest index on ties
        // (matches jnp.argmin); |x| folds into VOP3 abs modifiers
        float m01 = (fabsf(e1) < fabsf(e0)) ? e1 : e0;
        float m23 = (fabsf(e3) < fabsf(e2)) ? e3 : e2;
        float m45 = (fabsf(e5) < fabsf(e4)) ? e5 : e4;
        float m67 = (fabsf(e7) < fabsf(e6)) ? e7 : e6;
        float mA  = (fabsf(m23) < fabsf(m01)) ? m23 : m01;
        float mB  = (fabsf(m67) < fabsf(m45)) ? m67 : m45;
        float bd  = (fabsf(mB)  < fabsf(mA))  ? mB  : mA;
        const float res = c + bd;
        if (j == 0) R.x = res; else if (j == 1) R.y = res;
        else if (j == 2) R.z = res; else R.w = res;
    }
    return R;
}

// ---------------- 3-dispatch path: one SWF iteration per dispatch ----------
// 64x64 output tile. Stage 68x68 with zero-padded +-2 halo, compute, store
// straight to global (every output pixel in-image). LDS 18496 B ->
// 8 blocks/CU (threads-limited), 32 waves/CU; 4 swf4 segments per thread.
__global__ __launch_bounds__(256) void swf_step1(const float* __restrict__ in,
                                                 float* __restrict__ out) {
    __shared__ __align__(16) float A[68 * 68];

    const int tid = threadIdx.x;
    const int tx0 = blockIdx.x * 64;
    const int ty0 = blockIdx.y * 64;
    const long long base = (long long)blockIdx.z * (768 * 768);
    const float* inp = in + base;

    // stage rows ty0-2..ty0+65, cols tx0-2..tx0+65, zero-padded.
    // float2 granularity: global col tx0-2 is even -> 8B aligned.
    const bool intr = (tx0 >= 2) && (ty0 >= 2) &&
                      (tx0 + 66 <= 768) && (ty0 + 66 <= 768);
    if (intr) {
        // interior: no bounds checks at all
        const float* g0 = inp + (long long)(ty0 - 2) * 768 + (tx0 - 2);
        for (int i = tid; i < 68 * 34; i += 256) {
            const int ly  = i / 34;
            const int lx2 = (i - ly * 34) * 2;
            *(f2v*)(A + ly * 68 + lx2) = *(const f2v*)(g0 + ly * 768 + lx2);
        }
    } else {
        for (int i = tid; i < 68 * 34; i += 256) {
            const int ly  = i / 34;
            const int lx2 = i - ly * 34;
            const int gy  = ty0 + ly - 2;
            const int gx  = tx0 + lx2 * 2 - 2;
            f2v v = {0.0f, 0.0f};
            if ((unsigned)gy < 768u) {
                const float* g = inp + gy * 768 + gx;
                if ((unsigned)gx < 767u) {            // both lanes inside
                    v = *(const f2v*)g;
                } else {                               // x-edge: per-lane
                    if ((unsigned)gx < 768u)       v.x = g[0];
                    if ((unsigned)(gx + 1) < 768u) v.y = g[1];
                }
            }
            *(f2v*)(A + ly * 68 + lx2 * 2) = v;
        }
    }
    __syncthreads();

    float* op = out + base + (long long)ty0 * 768 + tx0;
    // NSEG = 64*16 = 1024 = exactly 4 full 256-thread passes (no tail).
    #pragma unroll 1
    for (int s = tid; s < 1024; s += 256) {
        const int y  = s >> 4;
        const int xs = (s & 15) * 4;
        f4v R = swf4<68>(A + y * 68 + xs);
        *(f4v*)(op + y * 768 + xs) = R;   // 16B-aligned: tx0%64==0, xs%4==0
    }
}

// ---------------- fused fallback (ws too small) ----------------------------
// One SWF iteration. X: (H2+4) x (W2+4) fp32 LDS tile (pitch W2+4), zero-pad.
// Y: H2 x W2 (pitch W2), zeroed outside the 768x768 image (gy0,gx0 = global
// coords of Y[0][0]); if LAST, write fp32 to outp (pitch 768).
template<int H2, int W2, bool LAST>
__device__ __forceinline__ void step(const float* __restrict__ X,
                                     float* __restrict__ Y,
                                     float* __restrict__ outp,
                                     int gy0, int gx0, int tid) {
    constexpr int PW = W2 + 4;
    constexpr int SC = W2 / 4;
    constexpr int NSEG = H2 * SC;

    const bool interior = (gy0 >= 0) && (gx0 >= 0) &&
                          (gy0 + H2 <= 768) && (gx0 + W2 <= 768);

    for (int s = tid; s < NSEG; s += 256) {
        const int y  = s / SC;
        const int xs = (s - y * SC) * 4;
        f4v R = swf4<PW>(X + y * PW + xs);

        if (LAST) {
            *(f4v*)(outp + y * 768 + xs) = R;
        } else if (interior) {
            *(f4v*)(Y + y * W2 + xs) = R;
        } else {
            const bool rowin = ((unsigned)(gy0 + y) < 768u);
            R.x = (rowin && (unsigned)(gx0 + xs + 0) < 768u) ? R.x : 0.0f;
            R.y = (rowin && (unsigned)(gx0 + xs + 1) < 768u) ? R.y : 0.0f;
            R.z = (rowin && (unsigned)(gx0 + xs + 2) < 768u) ? R.z : 0.0f;
            R.w = (rowin && (unsigned)(gx0 + xs + 3) < 768u) ? R.w : 0.0f;
            *(f4v*)(Y + y * W2 + xs) = R;
        }
    }
    __syncthreads();
}

__global__ __launch_bounds__(256) void swf_fused(const float* __restrict__ in,
                                                 float* __restrict__ out) {
    __shared__ __align__(16) float A[44 * 76];
    __shared__ __align__(16) float B[40 * 72];

    const int tid = threadIdx.x;
    const int tx0 = blockIdx.x * 64;
    const int ty0 = blockIdx.y * 32;
    const long long base = (long long)blockIdx.z * (768 * 768);
    const float* inp = in + base;

    for (int i = tid; i < 44 * 38; i += 256) {
        const int ly  = i / 38;
        const int lx2 = i - ly * 38;
        const int gy  = ty0 + ly - 6;
        const int gx  = tx0 + lx2 * 2 - 6;
        f2v v = {0.0f, 0.0f};
        if ((unsigned)gy < 768u) {
            const float* g = inp + gy * 768 + gx;
            if ((unsigned)gx < 767u) {
                v = *(const f2v*)g;
            } else {
                if ((unsigned)gx < 768u)       v.x = g[0];
                if ((unsigned)(gx + 1) < 768u) v.y = g[1];
            }
        }
        *(f2v*)(A + ly * 76 + lx2 * 2) = v;
    }
    __syncthreads();

    step<40, 72, false>(A, B, nullptr, ty0 - 4, tx0 - 4, tid);  // iter1: A->B
    step<36, 68, false>(B, A, nullptr, ty0 - 2, tx0 - 2, tid);  // iter2: B->A
    step<32, 64, true >(A, nullptr,                              // iter3: A->out
                        out + base + (long long)ty0 * 768 + tx0, ty0, tx0, tid);
}

extern "C" void kernel_launch(void* const* d_in, const int* in_sizes, int n_in,
                              void* d_out, int out_size, void* d_ws, size_t ws_size,
                              hipStream_t stream) {
    const float* x = (const float*)d_in[0];
    float* out = (float*)d_out;

    const size_t IMG_BYTES = (size_t)768 * 768 * 24 * sizeof(float); // 56.6 MB

    if (ws_size >= IMG_BYTES && d_ws != nullptr) {
        float* ws = (float*)d_ws;
        dim3 grid(768 / 64, 768 / 64, 24);   // 12 x 12 x 24 = 3456 blocks
        dim3 block(256);
        // iter1: x -> out, iter2: out -> ws, iter3: ws -> out.
        // Stream ordering makes each dispatch's writes visible to the next.
        swf_step1<<<grid, block, 0, stream>>>(x, out);
        swf_step1<<<grid, block, 0, stream>>>(out, ws);
        swf_step1<<<grid, block, 0, stream>>>(ws, out);
    } else {
        dim3 grid(768 / 64, 768 / 32, 24);   // 12 x 24 x 24 = 6912 blocks
        dim3 block(256);
        swf_fused<<<grid, block, 0, stream>>>(x, out);
    }
}

// Round 4
// 209.360 us; speedup vs baseline: 1.0994x; 1.0994x over previous
//
#include <hip/hip_runtime.h>
#include <math.h>

// Side-window filter, 3 iterations fused, FP32, bit-exact vs the np reference
// (verified absmax==0.0): each directional conv is a sequential fp32 FMA chain
// over taps in row-major (ky,kx) order, weights fp32(1/15), fp32(1/9),
// fp32(fp32(1/9)/9). Zero-padded taps are exact no-ops. Intermediates fp32;
// out-of-image intermediate pixels zeroed (next iteration zero-pads).
//
// Round 10: back to the round-1 fused 64x32 structure (best measured:
// 131.8 us/dispatch, VALUBusy 85%) — the 3-dispatch split lost twice
// (VGPR=32 codegen + 3x staging-convoy exposure, busy 49-55%). This round
// attacks the measured 47 lane-ops/px of codegen fat (172 measured vs ~125
// structural):
//  (a) chain heads are now muls: fmaf(w,x,0) == w*x bit-exactly here (all
//      window values >= +0: uniform(0,1) input, positive weights, +0 pads,
//      and c+(acc-c) stays >= +0) -> deletes 32 zero-inits per segment.
//  (b) swf4 split into two passes: A={L,R,U,D}, B={NW,NE,SW,SE}. 16 live
//      accumulators per pass instead of 32 -> fits the register budget with
//      no shuffling. The argmin tournament factors exactly along this split
//      (identical tree, tie order preserved). Pass B re-reads the 10 row
//      windows (LGKM pipe ~30% utilized, headroom); an asm memory clobber
//      between passes defeats load-CSE that would re-merge live ranges.
//  (c) per-segment s/SC magic-div replaced with incremental (y,xs) stepping.
//
// Direction supports (with the reference's normalization bug):
//   d0 L  = rows[-2..2] x cols[-2..0] * (1/15)
//   d1 R  = rows[-2..2] x cols[0..2]  * (1/15)
//   d2 U  = rows[-2..0] x cols[-2..2] * (1/15)
//   d3 D  = rows[0..2]  x cols[-2..2] * (1/15)
//   d4 NW = rows[-2..0] x cols[-2..0] * (1/9)
//   d5 NE = NW support * (1/81)   (bug: NE = new NW / 9)
//   d6 SW = rows[0..2]  x cols[-2..0] * (1/9)
//   d7 SE = SW support * (1/81)   (bug: SE = new SW / 9)

typedef float f4v __attribute__((ext_vector_type(4)));
typedef float f2v __attribute__((ext_vector_type(2), aligned(8)));

// Core math for 4 horizontally-adjacent pixels. rp points at the (-2,-2) tap
// of pixel 0 in an LDS tile of pitch PW floats (rows 16B-aligned). Each
// accumulator's op order (rows ascending, cols ascending within row) is the
// verified bit-exact chain — do not reorder within a chain.
template<int PW>
__device__ __forceinline__ f4v swf4(const float* __restrict__ rp) {
    const float w15 = 1.0f / 15.0f;
    const float w9  = 1.0f / 9.0f;
    const float w81 = (1.0f / 9.0f) / 9.0f;

    float ctr[4], mA[4];

    // ---- pass A: the four w15 box chains (L, R, U, D); 16 live accs ----
    {
        float aL[4], aR[4], aU[4], aD[4];
        #pragma unroll
        for (int r = 0; r < 5; r++) {
            const float* p = rp + r * PW;     // 16B-aligned
            f4v lo = *(const f4v*)p;
            f4v hi = *(const f4v*)(p + 4);
            float w[8] = {lo.x, lo.y, lo.z, lo.w, hi.x, hi.y, hi.z, hi.w};

            #pragma unroll
            for (int j = 0; j < 4; j++) {
                if (r == 0) {
                    // heads: w*x bit-identical to fmaf(w,x,+0) (data >= +0)
                    aL[j] = w15 * w[j + 0];
                    aL[j] = fmaf(w15, w[j + 1], aL[j]);
                    aL[j] = fmaf(w15, w[j + 2], aL[j]);
                    aR[j] = w15 * w[j + 2];
                    aR[j] = fmaf(w15, w[j + 3], aR[j]);
                    aR[j] = fmaf(w15, w[j + 4], aR[j]);
                    aU[j] = w15 * w[j + 0];
                    aU[j] = fmaf(w15, w[j + 1], aU[j]);
                    aU[j] = fmaf(w15, w[j + 2], aU[j]);
                    aU[j] = fmaf(w15, w[j + 3], aU[j]);
                    aU[j] = fmaf(w15, w[j + 4], aU[j]);
                } else {
                    aL[j] = fmaf(w15, w[j + 0], aL[j]);
                    aL[j] = fmaf(w15, w[j + 1], aL[j]);
                    aL[j] = fmaf(w15, w[j + 2], aL[j]);
                    aR[j] = fmaf(w15, w[j + 2], aR[j]);
                    aR[j] = fmaf(w15, w[j + 3], aR[j]);
                    aR[j] = fmaf(w15, w[j + 4], aR[j]);
                    if (r < 3) {
                        aU[j] = fmaf(w15, w[j + 0], aU[j]);
                        aU[j] = fmaf(w15, w[j + 1], aU[j]);
                        aU[j] = fmaf(w15, w[j + 2], aU[j]);
                        aU[j] = fmaf(w15, w[j + 3], aU[j]);
                        aU[j] = fmaf(w15, w[j + 4], aU[j]);
                    }
                    if (r == 2) {
                        aD[j] = w15 * w[j + 0];
                        aD[j] = fmaf(w15, w[j + 1], aD[j]);
                        aD[j] = fmaf(w15, w[j + 2], aD[j]);
                        aD[j] = fmaf(w15, w[j + 3], aD[j]);
                        aD[j] = fmaf(w15, w[j + 4], aD[j]);
                        ctr[j] = w[j + 2];
                    } else if (r > 2) {
                        aD[j] = fmaf(w15, w[j + 0], aD[j]);
                        aD[j] = fmaf(w15, w[j + 1], aD[j]);
                        aD[j] = fmaf(w15, w[j + 2], aD[j]);
                        aD[j] = fmaf(w15, w[j + 3], aD[j]);
                        aD[j] = fmaf(w15, w[j + 4], aD[j]);
                    }
                }
            }
        }
        // first half of the tournament: indices 0..3, strict < keeps the
        // lowest index on ties (matches jnp.argmin); |x| folds into VOP3 abs
        #pragma unroll
        for (int j = 0; j < 4; j++) {
            const float c = ctr[j];
            const float e0 = aL[j] - c, e1 = aR[j] - c;
            const float e2 = aU[j] - c, e3 = aD[j] - c;
            float m01 = (fabsf(e1) < fabsf(e0)) ? e1 : e0;
            float m23 = (fabsf(e3) < fabsf(e2)) ? e3 : e2;
            mA[j]     = (fabsf(m23) < fabsf(m01)) ? m23 : m01;
        }
    }

    // Defeat load-CSE across passes: without this the compiler keeps all 10
    // row-windows live from pass A into pass B and re-creates the register
    // pressure this split removes. Re-reading LDS is cheap (LGKM headroom).
    asm volatile("" ::: "memory");

    // ---- pass B: the diagonal chains (NW, NE, SW, SE); 16 live accs ----
    f4v R;
    {
        float nw[4], ne[4], sw[4], se[4];
        #pragma unroll
        for (int r = 0; r < 5; r++) {
            const float* p = rp + r * PW;
            f4v lo = *(const f4v*)p;
            f4v hi = *(const f4v*)(p + 4);
            float w[8] = {lo.x, lo.y, lo.z, lo.w, hi.x, hi.y, hi.z, hi.w};

            #pragma unroll
            for (int j = 0; j < 4; j++) {
                if (r == 0) {
                    nw[j] = w9 * w[j + 0];
                    nw[j] = fmaf(w9,  w[j + 1], nw[j]);
                    nw[j] = fmaf(w9,  w[j + 2], nw[j]);
                    ne[j] = w81 * w[j + 0];
                    ne[j] = fmaf(w81, w[j + 1], ne[j]);
                    ne[j] = fmaf(w81, w[j + 2], ne[j]);
                } else if (r < 3) {
                    nw[j] = fmaf(w9,  w[j + 0], nw[j]);
                    nw[j] = fmaf(w9,  w[j + 1], nw[j]);
                    nw[j] = fmaf(w9,  w[j + 2], nw[j]);
                    ne[j] = fmaf(w81, w[j + 0], ne[j]);
                    ne[j] = fmaf(w81, w[j + 1], ne[j]);
                    ne[j] = fmaf(w81, w[j + 2], ne[j]);
                }
                if (r == 2) {
                    sw[j] = w9 * w[j + 0];
                    sw[j] = fmaf(w9,  w[j + 1], sw[j]);
                    sw[j] = fmaf(w9,  w[j + 2], sw[j]);
                    se[j] = w81 * w[j + 0];
                    se[j] = fmaf(w81, w[j + 1], se[j]);
                    se[j] = fmaf(w81, w[j + 2], se[j]);
                } else if (r > 2) {
                    sw[j] = fmaf(w9,  w[j + 0], sw[j]);
                    sw[j] = fmaf(w9,  w[j + 1], sw[j]);
                    sw[j] = fmaf(w9,  w[j + 2], sw[j]);
                    se[j] = fmaf(w81, w[j + 0], se[j]);
                    se[j] = fmaf(w81, w[j + 1], se[j]);
                    se[j] = fmaf(w81, w[j + 2], se[j]);
                }
            }
        }
        // second half + final: identical tree to the verified single-pass form
        #pragma unroll
        for (int j = 0; j < 4; j++) {
            const float c = ctr[j];
            const float e4 = nw[j] - c, e5 = ne[j] - c;
            const float e6 = sw[j] - c, e7 = se[j] - c;
            float m45 = (fabsf(e5) < fabsf(e4)) ? e5 : e4;
            float m67 = (fabsf(e7) < fabsf(e6)) ? e7 : e6;
            float mB  = (fabsf(m67) < fabsf(m45)) ? m67 : m45;
            float bd  = (fabsf(mB)  < fabsf(mA[j])) ? mB : mA[j];
            const float res = c + bd;
            if (j == 0) R.x = res; else if (j == 1) R.y = res;
            else if (j == 2) R.z = res; else R.w = res;
        }
    }
    return R;
}

// One SWF iteration. X: (H2+4) x (W2+4) fp32 LDS tile (pitch W2+4), zero-pad.
// Y: H2 x W2 (pitch W2), zeroed outside the 768x768 image (gy0,gx0 = global
// coords of Y[0][0]); if LAST, write fp32 to outp (pitch 768).
template<int H2, int W2, bool LAST>
__device__ __forceinline__ void step(const float* __restrict__ X,
                                     float* __restrict__ Y,
                                     float* __restrict__ outp,
                                     int gy0, int gx0, int tid) {
    constexpr int PW  = W2 + 4;
    constexpr int SC  = W2 / 4;
    constexpr int NSEG = H2 * SC;
    constexpr int DY  = 256 / SC;         // y advance per grid-stride step
    constexpr int DXF = (256 % SC) * 4;   // xs advance (floats), < W2

    const bool interior = (gy0 >= 0) && (gx0 >= 0) &&
                          (gy0 + H2 <= 768) && (gx0 + W2 <= 768);

    int y  = tid / SC;
    int xs = (tid - y * SC) * 4;
    #pragma unroll 1
    for (int s = tid; s < NSEG; s += 256) {
        f4v R = swf4<PW>(X + y * PW + xs);

        if (LAST) {
            *(f4v*)(outp + y * 768 + xs) = R;
        } else if (interior) {
            *(f4v*)(Y + y * W2 + xs) = R;
        } else {
            // zero outside the image: next iteration zero-pads at the boundary
            const bool rowin = ((unsigned)(gy0 + y) < 768u);
            R.x = (rowin && (unsigned)(gx0 + xs + 0) < 768u) ? R.x : 0.0f;
            R.y = (rowin && (unsigned)(gx0 + xs + 1) < 768u) ? R.y : 0.0f;
            R.z = (rowin && (unsigned)(gx0 + xs + 2) < 768u) ? R.z : 0.0f;
            R.w = (rowin && (unsigned)(gx0 + xs + 3) < 768u) ? R.w : 0.0f;
            *(f4v*)(Y + y * W2 + xs) = R;
        }

        xs += DXF;
        y  += DY;
        if (xs >= W2) { xs -= W2; y += 1; }
    }
    __syncthreads();
}

// LDS: A = 44x76 fp32 (iter1 input; reused as iter2 output 36x68) = 13376 B,
//      B = 40x72 fp32 (iter1 output = iter2 input) = 11520 B. Total 24896 B
//      -> 6 blocks/CU (24 waves/CU).
__global__ __launch_bounds__(256) void swf_fused(const float* __restrict__ in,
                                                 float* __restrict__ out) {
    __shared__ __align__(16) float A[44 * 76];
    __shared__ __align__(16) float B[40 * 72];

    const int tid = threadIdx.x;
    const int tx0 = blockIdx.x * 64;
    const int ty0 = blockIdx.y * 32;
    const long long base = (long long)blockIdx.z * (768 * 768);
    const float* inp = in + base;

    // load tile rows ty0-6..ty0+37, cols tx0-6..tx0+69, zero-padded.
    // float2 granularity: global col tx0-6 is even -> 8B aligned.
    for (int i = tid; i < 44 * 38; i += 256) {
        const int ly  = i / 38;
        const int lx2 = i - ly * 38;
        const int gy  = ty0 + ly - 6;
        const int gx  = tx0 + lx2 * 2 - 6;
        f2v v = {0.0f, 0.0f};
        if ((unsigned)gy < 768u) {
            const float* g = inp + gy * 768 + gx;
            if ((unsigned)gx < 767u) {            // both lanes inside
                v = *(const f2v*)g;
            } else {                               // x-edge: per-lane
                if ((unsigned)gx < 768u)       v.x = g[0];
                if ((unsigned)(gx + 1) < 768u) v.y = g[1];
            }
        }
        *(f2v*)(A + ly * 76 + lx2 * 2) = v;
    }
    __syncthreads();

    step<40, 72, false>(A, B, nullptr, ty0 - 4, tx0 - 4, tid);  // iter1: A->B
    step<36, 68, false>(B, A, nullptr, ty0 - 2, tx0 - 2, tid);  // iter2: B->A
    step<32, 64, true >(A, nullptr,                              // iter3: A->out
                        out + base + (long long)ty0 * 768 + tx0, ty0, tx0, tid);
}

extern "C" void kernel_launch(void* const* d_in, const int* in_sizes, int n_in,
                              void* d_out, int out_size, void* d_ws, size_t ws_size,
                              hipStream_t stream) {
    const float* x = (const float*)d_in[0];
    float* out = (float*)d_out;

    dim3 grid(768 / 64, 768 / 32, 24);   // 12 x 24 x 24 = 6912 blocks
    dim3 block(256);
    swf_fused<<<grid, block, 0, stream>>>(x, out);
}

// Round 5
// 195.021 us; speedup vs baseline: 1.1802x; 1.0735x over previous
//
#include <hip/hip_runtime.h>
#include <math.h>

// Side-window filter, 3 iterations fused, FP32, bit-exact vs the np reference
// (verified absmax==0.0): each directional conv is a sequential fp32 FMA chain
// over taps in row-major (ky,kx) order, weights fp32(1/15), fp32(1/9),
// fp32(fp32(1/9)/9). Zero-padded taps are exact no-ops; chain heads are muls
// (== fmaf onto +0, verified bit-exact in round 4). Intermediates fp32;
// out-of-image intermediate pixels zeroed (next iteration zero-pads).
//
// Round 11: exact-sharing restructure. Four BITWISE identities (same support,
// same weight, same row-major chain):
//   L[x,y] == R[x-2,y]   (w15, 5 rows x 3 cols)
//   U[x,y] == D[x,y-2]   (w15, 3 rows x 5 cols)
//   NW[x,y]== SW[x,y-2]  (w9,  3x3, cols x-2..x)
//   NE[x,y]== SE[x,y-2]  (w81, same support as NW/SW — the reference bug)
// Threads own 4-wide column chains stepping y by 2 (parity pairs), carrying
// D/SW/SE of row y-2 in 12 registers; L comes from the same row's R array
// (R computed at 6 positions x0-2..x0+3 — same 2 ds_read_b128 window as
// before, no extra LDS traffic). First row of each chain computes U/NW/NE
// fresh (identical chains -> exact). Per-4px row: 354 FMA (full) / 222
// (shared) vs 480 before; effective FMA/px 96 -> ~74.
//
// Direction supports (with the reference's normalization bug):
//   d0 L  = rows[-2..2] x cols[-2..0] * (1/15)
//   d1 R  = rows[-2..2] x cols[0..2]  * (1/15)
//   d2 U  = rows[-2..0] x cols[-2..2] * (1/15)
//   d3 D  = rows[0..2]  x cols[-2..2] * (1/15)
//   d4 NW = rows[-2..0] x cols[-2..0] * (1/9)
//   d5 NE = NW support * (1/81)
//   d6 SW = rows[0..2]  x cols[-2..0] * (1/9)
//   d7 SE = SW support * (1/81)

typedef float f4v __attribute__((ext_vector_type(4)));
typedef float f2v __attribute__((ext_vector_type(2), aligned(8)));

// Per-row core for output row y of a 4-wide strip at x0. rp = X + y*PW + x0
// (X row y holds tap row y-2; X col x0 holds tap col x0-2).
//   Rv[0..5]: R at x = x0-2..x0+3  (w15; taps cols x..x+2, rows y-2..y+2)
//   Dv/SWv/SEv[0..3]: D/SW/SE at x0+j (tap rows y..y+2)
//   if FULL: Uv/NWv/NEv[0..3]       (tap rows y-2..y)
//   ctr[j] = X(y, x0+j)
// Chain order per accumulator: tap rows ascending, cols ascending — the
// verified bit-exact order. Do not reorder within a chain.
template<int PW, bool FULL>
__device__ __forceinline__ void swf_row(const float* __restrict__ rp,
        float* Rv, float* Dv, float* SWv, float* SEv,
        float* Uv, float* NWv, float* NEv, float* ctr) {
    const float w15 = 1.0f / 15.0f;
    const float w9  = 1.0f / 9.0f;
    const float w81 = (1.0f / 9.0f) / 9.0f;

    #pragma unroll
    for (int r = 0; r < 5; r++) {
        const float* p = rp + r * PW;     // 16B-aligned
        f4v lo = *(const f4v*)p;
        f4v hi = *(const f4v*)(p + 4);
        float w[8] = {lo.x, lo.y, lo.z, lo.w, hi.x, hi.y, hi.z, hi.w};

        // R chains at 6 positions; w[q] = tap col x0-2+q
        #pragma unroll
        for (int q = 0; q < 6; q++) {
            float a = (r == 0) ? (w15 * w[q]) : fmaf(w15, w[q], Rv[q]);
            a = fmaf(w15, w[q + 1], a);
            a = fmaf(w15, w[q + 2], a);
            Rv[q] = a;
        }

        #pragma unroll
        for (int j = 0; j < 4; j++) {
            if (FULL && r < 3) {           // U, NW, NE (tap rows y-2..y)
                float u = (r == 0) ? (w15 * w[j]) : fmaf(w15, w[j], Uv[j]);
                u = fmaf(w15, w[j + 1], u);
                u = fmaf(w15, w[j + 2], u);
                u = fmaf(w15, w[j + 3], u);
                u = fmaf(w15, w[j + 4], u);
                Uv[j] = u;
                float nw = (r == 0) ? (w9 * w[j]) : fmaf(w9, w[j], NWv[j]);
                nw = fmaf(w9, w[j + 1], nw);
                nw = fmaf(w9, w[j + 2], nw);
                NWv[j] = nw;
                float ne = (r == 0) ? (w81 * w[j]) : fmaf(w81, w[j], NEv[j]);
                ne = fmaf(w81, w[j + 1], ne);
                ne = fmaf(w81, w[j + 2], ne);
                NEv[j] = ne;
            }
            if (r >= 2) {                  // D, SW, SE (tap rows y..y+2)
                float d = (r == 2) ? (w15 * w[j]) : fmaf(w15, w[j], Dv[j]);
                d = fmaf(w15, w[j + 1], d);
                d = fmaf(w15, w[j + 2], d);
                d = fmaf(w15, w[j + 3], d);
                d = fmaf(w15, w[j + 4], d);
                Dv[j] = d;
                float sw = (r == 2) ? (w9 * w[j]) : fmaf(w9, w[j], SWv[j]);
                sw = fmaf(w9, w[j + 1], sw);
                sw = fmaf(w9, w[j + 2], sw);
                SWv[j] = sw;
                float se = (r == 2) ? (w81 * w[j]) : fmaf(w81, w[j], SEv[j]);
                se = fmaf(w81, w[j + 1], se);
                se = fmaf(w81, w[j + 2], se);
                SEv[j] = se;
                if (r == 2) ctr[j] = w[j + 2];
            }
        }
    }
}

// argmin tournament + store for one 4-px row. e-order (L,R,U,D,NW,NE,SW,SE)
// and strict-< tree identical to the verified kernel (lowest index on ties).
template<int W2, bool LAST>
__device__ __forceinline__ void emit_store(const float* Rv,
        const float* Ua, const float* NWa, const float* NEa,
        const float* Dn, const float* SWn, const float* SEn, const float* ctr,
        float* __restrict__ Y, float* __restrict__ outp,
        int y, int x0, int gy0, int gx0, bool interior) {
    f4v R;
    #pragma unroll
    for (int j = 0; j < 4; j++) {
        const float c  = ctr[j];
        const float e0 = Rv[j]     - c;   // L  == R[x-2] (same row)
        const float e1 = Rv[j + 2] - c;   // R
        const float e2 = Ua[j]     - c;   // U  (fresh or D[y-2])
        const float e3 = Dn[j]     - c;   // D
        const float e4 = NWa[j]    - c;   // NW (fresh or SW[y-2])
        const float e5 = NEa[j]    - c;   // NE (fresh or SE[y-2])
        const float e6 = SWn[j]    - c;   // SW
        const float e7 = SEn[j]    - c;   // SE
        float m01 = (fabsf(e1) < fabsf(e0)) ? e1 : e0;
        float m23 = (fabsf(e3) < fabsf(e2)) ? e3 : e2;
        float m45 = (fabsf(e5) < fabsf(e4)) ? e5 : e4;
        float m67 = (fabsf(e7) < fabsf(e6)) ? e7 : e6;
        float mA  = (fabsf(m23) < fabsf(m01)) ? m23 : m01;
        float mB  = (fabsf(m67) < fabsf(m45)) ? m67 : m45;
        float bd  = (fabsf(mB)  < fabsf(mA))  ? mB  : mA;
        const float res = c + bd;
        if (j == 0) R.x = res; else if (j == 1) R.y = res;
        else if (j == 2) R.z = res; else R.w = res;
    }
    if (LAST) {
        *(f4v*)(outp + y * 768 + x0) = R;
    } else if (interior) {
        *(f4v*)(Y + y * W2 + x0) = R;
    } else {
        // zero outside the image: next iteration zero-pads at the boundary
        const bool rowin = ((unsigned)(gy0 + y) < 768u);
        R.x = (rowin && (unsigned)(gx0 + x0 + 0) < 768u) ? R.x : 0.0f;
        R.y = (rowin && (unsigned)(gx0 + x0 + 1) < 768u) ? R.y : 0.0f;
        R.z = (rowin && (unsigned)(gx0 + x0 + 2) < 768u) ? R.z : 0.0f;
        R.w = (rowin && (unsigned)(gx0 + x0 + 3) < 768u) ? R.w : 0.0f;
        *(f4v*)(Y + y * W2 + x0) = R;
    }
}

// One SWF iteration, parity-chain mapping. X: (H2+4) x (W2+4) LDS tile
// (pitch W2+4, zero-pad). Threads -> (strip, chain): strip = 4-wide column,
// chain walks rows y0, y0+2, ... within a band of BH rows; two parity chains
// cover a band. First row of a chain is FULL (computes U/NW/NE fresh);
// later rows reuse the ring (D/SW/SE of y-2) — bitwise identical values.
template<int H2, int W2, bool LAST>
__device__ __forceinline__ void stepv(const float* __restrict__ X,
                                      float* __restrict__ Y,
                                      float* __restrict__ outp,
                                      int gy0, int gx0, int tid) {
    constexpr int PW     = W2 + 4;
    constexpr int STRIPS = W2 / 4;                    // 18 / 17 / 16
    constexpr int BA     = 256 / (2 * STRIPS);        // bands: 7 / 7 / 8
    constexpr int BH     = (((H2 + BA - 1) / BA) + 1) & ~1;  // 6 / 6 / 4
    static_assert(BA * BH >= H2, "bands must cover the tile");

    const bool interior = (gy0 >= 0) && (gx0 >= 0) &&
                          (gy0 + H2 <= 768) && (gx0 + W2 <= 768);

    const int chain = tid / STRIPS;
    const int strip = tid - chain * STRIPS;
    if (chain < 2 * BA) {
        const int band = chain >> 1;
        const int par  = chain & 1;
        const int x0   = strip * 4;
        int y = band * BH + par;
        const int yEnd = (band * BH + BH < H2) ? (band * BH + BH) : H2;
        if (y < yEnd) {
            float Rv[6], Dn[4], SWn[4], SEn[4], Uv[4], NWv[4], NEv[4], ctr[4];
            float pD[4], pSW[4], pSE[4];
            // full first row of the chain
            swf_row<PW, true>(X + y * PW + x0, Rv, Dn, SWn, SEn, Uv, NWv, NEv, ctr);
            emit_store<W2, LAST>(Rv, Uv, NWv, NEv, Dn, SWn, SEn, ctr,
                                 Y, outp, y, x0, gy0, gx0, interior);
            #pragma unroll
            for (int j = 0; j < 4; j++) { pD[j] = Dn[j]; pSW[j] = SWn[j]; pSE[j] = SEn[j]; }
            // shared rows (ring provides U/NW/NE); <= 2 iterations for BH<=6
            #pragma unroll
            for (int it = 1; it < BH / 2; it++) {
                y += 2;
                if (y < yEnd) {
                    swf_row<PW, false>(X + y * PW + x0, Rv, Dn, SWn, SEn,
                                       Uv, NWv, NEv, ctr);
                    emit_store<W2, LAST>(Rv, pD, pSW, pSE, Dn, SWn, SEn, ctr,
                                         Y, outp, y, x0, gy0, gx0, interior);
                    #pragma unroll
                    for (int j = 0; j < 4; j++) { pD[j] = Dn[j]; pSW[j] = SWn[j]; pSE[j] = SEn[j]; }
                }
            }
        }
    }
    __syncthreads();
}

// LDS: A = 44x76 fp32 (iter1 input; reused as iter2 output 36x68) = 13376 B,
//      B = 40x72 fp32 (iter1 output = iter2 input) = 11520 B. Total 24896 B
//      -> 6 blocks/CU (24 waves/CU).
__global__ __launch_bounds__(256) void swf_fused(const float* __restrict__ in,
                                                 float* __restrict__ out) {
    __shared__ __align__(16) float A[44 * 76];
    __shared__ __align__(16) float B[40 * 72];

    const int tid = threadIdx.x;
    const int tx0 = blockIdx.x * 64;
    const int ty0 = blockIdx.y * 32;
    const long long base = (long long)blockIdx.z * (768 * 768);
    const float* inp = in + base;

    // load tile rows ty0-6..ty0+37, cols tx0-6..tx0+69, zero-padded.
    // float2 granularity: global col tx0-6 is even -> 8B aligned.
    for (int i = tid; i < 44 * 38; i += 256) {
        const int ly  = i / 38;
        const int lx2 = i - ly * 38;
        const int gy  = ty0 + ly - 6;
        const int gx  = tx0 + lx2 * 2 - 6;
        f2v v = {0.0f, 0.0f};
        if ((unsigned)gy < 768u) {
            const float* g = inp + gy * 768 + gx;
            if ((unsigned)gx < 767u) {            // both lanes inside
                v = *(const f2v*)g;
            } else {                               // x-edge: per-lane
                if ((unsigned)gx < 768u)       v.x = g[0];
                if ((unsigned)(gx + 1) < 768u) v.y = g[1];
            }
        }
        *(f2v*)(A + ly * 76 + lx2 * 2) = v;
    }
    __syncthreads();

    stepv<40, 72, false>(A, B, nullptr, ty0 - 4, tx0 - 4, tid);  // iter1: A->B
    stepv<36, 68, false>(B, A, nullptr, ty0 - 2, tx0 - 2, tid);  // iter2: B->A
    stepv<32, 64, true >(A, nullptr,                              // iter3: A->out
                         out + base + (long long)ty0 * 768 + tx0, ty0, tx0, tid);
}

extern "C" void kernel_launch(void* const* d_in, const int* in_sizes, int n_in,
                              void* d_out, int out_size, void* d_ws, size_t ws_size,
                              hipStream_t stream) {
    const float* x = (const float*)d_in[0];
    float* out = (float*)d_out;

    dim3 grid(768 / 64, 768 / 32, 24);   // 12 x 24 x 24 = 6912 blocks
    dim3 block(256);
    swf_fused<<<grid, block, 0, stream>>>(x, out);
}

// Round 6
// 187.188 us; speedup vs baseline: 1.2296x; 1.0418x over previous
//
#include <hip/hip_runtime.h>
#include <math.h>

// Side-window filter, 3 iterations fused, FP32, bit-exact vs the np reference
// (verified absmax==0.0): each directional conv is a sequential fp32 FMA chain
// over taps in row-major (ky,kx) order, weights fp32(1/15), fp32(1/9),
// fp32(fp32(1/9)/9). Zero-padded taps are exact no-ops; chain heads are muls
// (== fmaf onto +0, verified bit-exact in round 4). Intermediates fp32;
// out-of-image intermediate pixels zeroed (next iteration zero-pads).
//
// Round 12: __launch_bounds__(256, 6). Evidence: VGPR_Count pinned at 40
// across three structurally different kernels while this code has ~54
// simultaneously-live floats -> the default 8-wave/SIMD register target
// (64-reg unified VGPR/AGPR budget) forces surplus live values into
// v_accvgpr_read/write shuffles, each a full VALU issue slot. This matches
// the ~40 us gap between structural issue (~63 us) and measured (~103.5 us).
// LDS (25 KB) caps occupancy at 6 blocks/CU regardless, so targeting
// 6 waves/SIMD raises the register cap to ~85 for free. Math untouched.
//
// Round 11 (kept): exact-sharing restructure. Four BITWISE identities:
//   L[x,y] == R[x-2,y]   (w15, 5 rows x 3 cols)
//   U[x,y] == D[x,y-2]   (w15, 3 rows x 5 cols)
//   NW[x,y]== SW[x,y-2]  (w9,  3x3, cols x-2..x)
//   NE[x,y]== SE[x,y-2]  (w81, same support as NW/SW — the reference bug)
// Threads own 4-wide column chains stepping y by 2 (parity pairs), carrying
// D/SW/SE of row y-2 in 12 registers; L comes from the same row's R array
// (R computed at 6 positions x0-2..x0+3). First row of each chain computes
// U/NW/NE fresh (identical chains -> exact).
//
// Direction supports (with the reference's normalization bug):
//   d0 L  = rows[-2..2] x cols[-2..0] * (1/15)
//   d1 R  = rows[-2..2] x cols[0..2]  * (1/15)
//   d2 U  = rows[-2..0] x cols[-2..2] * (1/15)
//   d3 D  = rows[0..2]  x cols[-2..2] * (1/15)
//   d4 NW = rows[-2..0] x cols[-2..0] * (1/9)
//   d5 NE = NW support * (1/81)
//   d6 SW = rows[0..2]  x cols[-2..0] * (1/9)
//   d7 SE = SW support * (1/81)

typedef float f4v __attribute__((ext_vector_type(4)));
typedef float f2v __attribute__((ext_vector_type(2), aligned(8)));

// Per-row core for output row y of a 4-wide strip at x0. rp = X + y*PW + x0
// (X row y holds tap row y-2; X col x0 holds tap col x0-2).
//   Rv[0..5]: R at x = x0-2..x0+3  (w15; taps cols x..x+2, rows y-2..y+2)
//   Dv/SWv/SEv[0..3]: D/SW/SE at x0+j (tap rows y..y+2)
//   if FULL: Uv/NWv/NEv[0..3]       (tap rows y-2..y)
//   ctr[j] = X(y, x0+j)
// Chain order per accumulator: tap rows ascending, cols ascending — the
// verified bit-exact order. Do not reorder within a chain.
template<int PW, bool FULL>
__device__ __forceinline__ void swf_row(const float* __restrict__ rp,
        float* Rv, float* Dv, float* SWv, float* SEv,
        float* Uv, float* NWv, float* NEv, float* ctr) {
    const float w15 = 1.0f / 15.0f;
    const float w9  = 1.0f / 9.0f;
    const float w81 = (1.0f / 9.0f) / 9.0f;

    #pragma unroll
    for (int r = 0; r < 5; r++) {
        const float* p = rp + r * PW;     // 16B-aligned
        f4v lo = *(const f4v*)p;
        f4v hi = *(const f4v*)(p + 4);
        float w[8] = {lo.x, lo.y, lo.z, lo.w, hi.x, hi.y, hi.z, hi.w};

        // R chains at 6 positions; w[q] = tap col x0-2+q
        #pragma unroll
        for (int q = 0; q < 6; q++) {
            float a = (r == 0) ? (w15 * w[q]) : fmaf(w15, w[q], Rv[q]);
            a = fmaf(w15, w[q + 1], a);
            a = fmaf(w15, w[q + 2], a);
            Rv[q] = a;
        }

        #pragma unroll
        for (int j = 0; j < 4; j++) {
            if (FULL && r < 3) {           // U, NW, NE (tap rows y-2..y)
                float u = (r == 0) ? (w15 * w[j]) : fmaf(w15, w[j], Uv[j]);
                u = fmaf(w15, w[j + 1], u);
                u = fmaf(w15, w[j + 2], u);
                u = fmaf(w15, w[j + 3], u);
                u = fmaf(w15, w[j + 4], u);
                Uv[j] = u;
                float nw = (r == 0) ? (w9 * w[j]) : fmaf(w9, w[j], NWv[j]);
                nw = fmaf(w9, w[j + 1], nw);
                nw = fmaf(w9, w[j + 2], nw);
                NWv[j] = nw;
                float ne = (r == 0) ? (w81 * w[j]) : fmaf(w81, w[j], NEv[j]);
                ne = fmaf(w81, w[j + 1], ne);
                ne = fmaf(w81, w[j + 2], ne);
                NEv[j] = ne;
            }
            if (r >= 2) {                  // D, SW, SE (tap rows y..y+2)
                float d = (r == 2) ? (w15 * w[j]) : fmaf(w15, w[j], Dv[j]);
                d = fmaf(w15, w[j + 1], d);
                d = fmaf(w15, w[j + 2], d);
                d = fmaf(w15, w[j + 3], d);
                d = fmaf(w15, w[j + 4], d);
                Dv[j] = d;
                float sw = (r == 2) ? (w9 * w[j]) : fmaf(w9, w[j], SWv[j]);
                sw = fmaf(w9, w[j + 1], sw);
                sw = fmaf(w9, w[j + 2], sw);
                SWv[j] = sw;
                float se = (r == 2) ? (w81 * w[j]) : fmaf(w81, w[j], SEv[j]);
                se = fmaf(w81, w[j + 1], se);
                se = fmaf(w81, w[j + 2], se);
                SEv[j] = se;
                if (r == 2) ctr[j] = w[j + 2];
            }
        }
    }
}

// argmin tournament + store for one 4-px row. e-order (L,R,U,D,NW,NE,SW,SE)
// and strict-< tree identical to the verified kernel (lowest index on ties).
template<int W2, bool LAST>
__device__ __forceinline__ void emit_store(const float* Rv,
        const float* Ua, const float* NWa, const float* NEa,
        const float* Dn, const float* SWn, const float* SEn, const float* ctr,
        float* __restrict__ Y, float* __restrict__ outp,
        int y, int x0, int gy0, int gx0, bool interior) {
    f4v R;
    #pragma unroll
    for (int j = 0; j < 4; j++) {
        const float c  = ctr[j];
        const float e0 = Rv[j]     - c;   // L  == R[x-2] (same row)
        const float e1 = Rv[j + 2] - c;   // R
        const float e2 = Ua[j]     - c;   // U  (fresh or D[y-2])
        const float e3 = Dn[j]     - c;   // D
        const float e4 = NWa[j]    - c;   // NW (fresh or SW[y-2])
        const float e5 = NEa[j]    - c;   // NE (fresh or SE[y-2])
        const float e6 = SWn[j]    - c;   // SW
        const float e7 = SEn[j]    - c;   // SE
        float m01 = (fabsf(e1) < fabsf(e0)) ? e1 : e0;
        float m23 = (fabsf(e3) < fabsf(e2)) ? e3 : e2;
        float m45 = (fabsf(e5) < fabsf(e4)) ? e5 : e4;
        float m67 = (fabsf(e7) < fabsf(e6)) ? e7 : e6;
        float mA  = (fabsf(m23) < fabsf(m01)) ? m23 : m01;
        float mB  = (fabsf(m67) < fabsf(m45)) ? m67 : m45;
        float bd  = (fabsf(mB)  < fabsf(mA))  ? mB  : mA;
        const float res = c + bd;
        if (j == 0) R.x = res; else if (j == 1) R.y = res;
        else if (j == 2) R.z = res; else R.w = res;
    }
    if (LAST) {
        *(f4v*)(outp + y * 768 + x0) = R;
    } else if (interior) {
        *(f4v*)(Y + y * W2 + x0) = R;
    } else {
        // zero outside the image: next iteration zero-pads at the boundary
        const bool rowin = ((unsigned)(gy0 + y) < 768u);
        R.x = (rowin && (unsigned)(gx0 + x0 + 0) < 768u) ? R.x : 0.0f;
        R.y = (rowin && (unsigned)(gx0 + x0 + 1) < 768u) ? R.y : 0.0f;
        R.z = (rowin && (unsigned)(gx0 + x0 + 2) < 768u) ? R.z : 0.0f;
        R.w = (rowin && (unsigned)(gx0 + x0 + 3) < 768u) ? R.w : 0.0f;
        *(f4v*)(Y + y * W2 + x0) = R;
    }
}

// One SWF iteration, parity-chain mapping. X: (H2+4) x (W2+4) LDS tile
// (pitch W2+4, zero-pad). Threads -> (strip, chain): strip = 4-wide column,
// chain walks rows y0, y0+2, ... within a band of BH rows; two parity chains
// cover a band. First row of a chain is FULL (computes U/NW/NE fresh);
// later rows reuse the ring (D/SW/SE of y-2) — bitwise identical values.
template<int H2, int W2, bool LAST>
__device__ __forceinline__ void stepv(const float* __restrict__ X,
                                      float* __restrict__ Y,
                                      float* __restrict__ outp,
                                      int gy0, int gx0, int tid) {
    constexpr int PW     = W2 + 4;
    constexpr int STRIPS = W2 / 4;                    // 18 / 17 / 16
    constexpr int BA     = 256 / (2 * STRIPS);        // bands: 7 / 7 / 8
    constexpr int BH     = (((H2 + BA - 1) / BA) + 1) & ~1;  // 6 / 6 / 4
    static_assert(BA * BH >= H2, "bands must cover the tile");

    const bool interior = (gy0 >= 0) && (gx0 >= 0) &&
                          (gy0 + H2 <= 768) && (gx0 + W2 <= 768);

    const int chain = tid / STRIPS;
    const int strip = tid - chain * STRIPS;
    if (chain < 2 * BA) {
        const int band = chain >> 1;
        const int par  = chain & 1;
        const int x0   = strip * 4;
        int y = band * BH + par;
        const int yEnd = (band * BH + BH < H2) ? (band * BH + BH) : H2;
        if (y < yEnd) {
            float Rv[6], Dn[4], SWn[4], SEn[4], Uv[4], NWv[4], NEv[4], ctr[4];
            float pD[4], pSW[4], pSE[4];
            // full first row of the chain
            swf_row<PW, true>(X + y * PW + x0, Rv, Dn, SWn, SEn, Uv, NWv, NEv, ctr);
            emit_store<W2, LAST>(Rv, Uv, NWv, NEv, Dn, SWn, SEn, ctr,
                                 Y, outp, y, x0, gy0, gx0, interior);
            #pragma unroll
            for (int j = 0; j < 4; j++) { pD[j] = Dn[j]; pSW[j] = SWn[j]; pSE[j] = SEn[j]; }
            // shared rows (ring provides U/NW/NE); <= 2 iterations for BH<=6
            #pragma unroll
            for (int it = 1; it < BH / 2; it++) {
                y += 2;
                if (y < yEnd) {
                    swf_row<PW, false>(X + y * PW + x0, Rv, Dn, SWn, SEn,
                                       Uv, NWv, NEv, ctr);
                    emit_store<W2, LAST>(Rv, pD, pSW, pSE, Dn, SWn, SEn, ctr,
                                         Y, outp, y, x0, gy0, gx0, interior);
                    #pragma unroll
                    for (int j = 0; j < 4; j++) { pD[j] = Dn[j]; pSW[j] = SWn[j]; pSE[j] = SEn[j]; }
                }
            }
        }
    }
    __syncthreads();
}

// LDS: A = 44x76 fp32 (iter1 input; reused as iter2 output 36x68) = 13376 B,
//      B = 40x72 fp32 (iter1 output = iter2 input) = 11520 B. Total 24896 B
//      -> 6 blocks/CU (24 waves/CU). launch_bounds(256,6) matches this
//      occupancy and raises the per-wave register cap 64 -> ~85 so the ~54
//      live floats fit without cross-file (AGPR) shuffle moves.
__global__ __launch_bounds__(256, 6) void swf_fused(const float* __restrict__ in,
                                                    float* __restrict__ out) {
    __shared__ __align__(16) float A[44 * 76];
    __shared__ __align__(16) float B[40 * 72];

    const int tid = threadIdx.x;
    const int tx0 = blockIdx.x * 64;
    const int ty0 = blockIdx.y * 32;
    const long long base = (long long)blockIdx.z * (768 * 768);
    const float* inp = in + base;

    // load tile rows ty0-6..ty0+37, cols tx0-6..tx0+69, zero-padded.
    // float2 granularity: global col tx0-6 is even -> 8B aligned.
    for (int i = tid; i < 44 * 38; i += 256) {
        const int ly  = i / 38;
        const int lx2 = i - ly * 38;
        const int gy  = ty0 + ly - 6;
        const int gx  = tx0 + lx2 * 2 - 6;
        f2v v = {0.0f, 0.0f};
        if ((unsigned)gy < 768u) {
            const float* g = inp + gy * 768 + gx;
            if ((unsigned)gx < 767u) {            // both lanes inside
                v = *(const f2v*)g;
            } else {                               // x-edge: per-lane
                if ((unsigned)gx < 768u)       v.x = g[0];
                if ((unsigned)(gx + 1) < 768u) v.y = g[1];
            }
        }
        *(f2v*)(A + ly * 76 + lx2 * 2) = v;
    }
    __syncthreads();

    stepv<40, 72, false>(A, B, nullptr, ty0 - 4, tx0 - 4, tid);  // iter1: A->B
    stepv<36, 68, false>(B, A, nullptr, ty0 - 2, tx0 - 2, tid);  // iter2: B->A
    stepv<32, 64, true >(A, nullptr,                              // iter3: A->out
                         out + base + (long long)ty0 * 768 + tx0, ty0, tx0, tid);
}

extern "C" void kernel_launch(void* const* d_in, const int* in_sizes, int n_in,
                              void* d_out, int out_size, void* d_ws, size_t ws_size,
                              hipStream_t stream) {
    const float* x = (const float*)d_in[0];
    float* out = (float*)d_out;

    dim3 grid(768 / 64, 768 / 32, 24);   // 12 x 24 x 24 = 6912 blocks
    dim3 block(256);
    swf_fused<<<grid, block, 0, stream>>>(x, out);
}

// Round 7
// 184.850 us; speedup vs baseline: 1.2452x; 1.0126x over previous
//
#include <hip/hip_runtime.h>
#include <math.h>

// Side-window filter, 3 iterations fused, FP32, bit-exact vs the np reference
// (verified absmax==0.0): each directional conv is a sequential fp32 FMA chain
// over taps in row-major (ky,kx) order, weights fp32(1/15), fp32(1/9),
// fp32(fp32(1/9)/9). Zero-padded taps are exact no-ops; chain heads are muls
// (== fmaf onto +0, verified bit-exact in round 4). Intermediates fp32;
// out-of-image intermediate pixels zeroed (next iteration zero-pads).
//
// Round 13: balanced piece mapping. Round 6 measured iter2's band mapping
// wasting ~25% of its issue at wave granularity (238/256 threads chained,
// 42 scheduled vs 36 useful rows, idle lanes riding in active waves).
// Each step's H2 x STRIPS row-tasks are now cut into EXACTLY 256 pieces of
// 2-3 same-parity consecutive rows (first row FULL, rest ring-shared; a FULL
// row at any y is bitwise-identical to ring values). Pieces are ordered
// len-2-first / run-fastest: all threads busy, waves length-pure except one
// boundary wave, lanes still read consecutive strips. Ring copies become
// straight-line variable rotation (no v_movs). Math untouched.
//
// Round 11 (kept): exact-sharing. Four BITWISE identities:
//   L[x,y] == R[x-2,y]   (w15, 5 rows x 3 cols)
//   U[x,y] == D[x,y-2]   (w15, 3 rows x 5 cols)
//   NW[x,y]== SW[x,y-2]  (w9,  3x3, cols x-2..x)
//   NE[x,y]== SE[x,y-2]  (w81, same support as NW/SW — the reference bug)
//
// Direction supports (with the reference's normalization bug):
//   d0 L  = rows[-2..2] x cols[-2..0] * (1/15)
//   d1 R  = rows[-2..2] x cols[0..2]  * (1/15)
//   d2 U  = rows[-2..0] x cols[-2..2] * (1/15)
//   d3 D  = rows[0..2]  x cols[-2..2] * (1/15)
//   d4 NW = rows[-2..0] x cols[-2..0] * (1/9)
//   d5 NE = NW support * (1/81)
//   d6 SW = rows[0..2]  x cols[-2..0] * (1/9)
//   d7 SE = SW support * (1/81)

typedef float f4v __attribute__((ext_vector_type(4)));
typedef float f2v __attribute__((ext_vector_type(2), aligned(8)));

// Per-row core for output row y of a 4-wide strip at x0. rp = X + y*PW + x0
// (X row y holds tap row y-2; X col x0 holds tap col x0-2).
//   Rv[0..5]: R at x = x0-2..x0+3  (w15; taps cols x..x+2, rows y-2..y+2)
//   Dv/SWv/SEv[0..3]: D/SW/SE at x0+j (tap rows y..y+2)
//   if FULL: Uv/NWv/NEv[0..3]       (tap rows y-2..y)
//   ctr[j] = X(y, x0+j)
// Chain order per accumulator: tap rows ascending, cols ascending — the
// verified bit-exact chain. Do not reorder within a chain.
template<int PW, bool FULL>
__device__ __forceinline__ void swf_row(const float* __restrict__ rp,
        float* Rv, float* Dv, float* SWv, float* SEv,
        float* Uv, float* NWv, float* NEv, float* ctr) {
    const float w15 = 1.0f / 15.0f;
    const float w9  = 1.0f / 9.0f;
    const float w81 = (1.0f / 9.0f) / 9.0f;

    #pragma unroll
    for (int r = 0; r < 5; r++) {
        const float* p = rp + r * PW;     // 16B-aligned
        f4v lo = *(const f4v*)p;
        f4v hi = *(const f4v*)(p + 4);
        float w[8] = {lo.x, lo.y, lo.z, lo.w, hi.x, hi.y, hi.z, hi.w};

        // R chains at 6 positions; w[q] = tap col x0-2+q
        #pragma unroll
        for (int q = 0; q < 6; q++) {
            float a = (r == 0) ? (w15 * w[q]) : fmaf(w15, w[q], Rv[q]);
            a = fmaf(w15, w[q + 1], a);
            a = fmaf(w15, w[q + 2], a);
            Rv[q] = a;
        }

        #pragma unroll
        for (int j = 0; j < 4; j++) {
            if (FULL && r < 3) {           // U, NW, NE (tap rows y-2..y)
                float u = (r == 0) ? (w15 * w[j]) : fmaf(w15, w[j], Uv[j]);
                u = fmaf(w15, w[j + 1], u);
                u = fmaf(w15, w[j + 2], u);
                u = fmaf(w15, w[j + 3], u);
                u = fmaf(w15, w[j + 4], u);
                Uv[j] = u;
                float nw = (r == 0) ? (w9 * w[j]) : fmaf(w9, w[j], NWv[j]);
                nw = fmaf(w9, w[j + 1], nw);
                nw = fmaf(w9, w[j + 2], nw);
                NWv[j] = nw;
                float ne = (r == 0) ? (w81 * w[j]) : fmaf(w81, w[j], NEv[j]);
                ne = fmaf(w81, w[j + 1], ne);
                ne = fmaf(w81, w[j + 2], ne);
                NEv[j] = ne;
            }
            if (r >= 2) {                  // D, SW, SE (tap rows y..y+2)
                float d = (r == 2) ? (w15 * w[j]) : fmaf(w15, w[j], Dv[j]);
                d = fmaf(w15, w[j + 1], d);
                d = fmaf(w15, w[j + 2], d);
                d = fmaf(w15, w[j + 3], d);
                d = fmaf(w15, w[j + 4], d);
                Dv[j] = d;
                float sw = (r == 2) ? (w9 * w[j]) : fmaf(w9, w[j], SWv[j]);
                sw = fmaf(w9, w[j + 1], sw);
                sw = fmaf(w9, w[j + 2], sw);
                SWv[j] = sw;
                float se = (r == 2) ? (w81 * w[j]) : fmaf(w81, w[j], SEv[j]);
                se = fmaf(w81, w[j + 1], se);
                se = fmaf(w81, w[j + 2], se);
                SEv[j] = se;
                if (r == 2) ctr[j] = w[j + 2];
            }
        }
    }
}

// argmin tournament + store for one 4-px row. e-order (L,R,U,D,NW,NE,SW,SE)
// and strict-< tree identical to the verified kernel (lowest index on ties).
template<int W2, bool LAST>
__device__ __forceinline__ void emit_store(const float* Rv,
        const float* Ua, const float* NWa, const float* NEa,
        const float* Dn, const float* SWn, const float* SEn, const float* ctr,
        float* __restrict__ Y, float* __restrict__ outp,
        int y, int x0, int gy0, int gx0, bool interior) {
    f4v R;
    #pragma unroll
    for (int j = 0; j < 4; j++) {
        const float c  = ctr[j];
        const float e0 = Rv[j]     - c;   // L  == R[x-2] (same row)
        const float e1 = Rv[j + 2] - c;   // R
        const float e2 = Ua[j]     - c;   // U  (fresh or D[y-2])
        const float e3 = Dn[j]     - c;   // D
        const float e4 = NWa[j]    - c;   // NW (fresh or SW[y-2])
        const float e5 = NEa[j]    - c;   // NE (fresh or SE[y-2])
        const float e6 = SWn[j]    - c;   // SW
        const float e7 = SEn[j]    - c;   // SE
        float m01 = (fabsf(e1) < fabsf(e0)) ? e1 : e0;
        float m23 = (fabsf(e3) < fabsf(e2)) ? e3 : e2;
        float m45 = (fabsf(e5) < fabsf(e4)) ? e5 : e4;
        float m67 = (fabsf(e7) < fabsf(e6)) ? e7 : e6;
        float mA  = (fabsf(m23) < fabsf(m01)) ? m23 : m01;
        float mB  = (fabsf(m67) < fabsf(m45)) ? m67 : m45;
        float bd  = (fabsf(mB)  < fabsf(mA))  ? mB  : mA;
        const float res = c + bd;
        if (j == 0) R.x = res; else if (j == 1) R.y = res;
        else if (j == 2) R.z = res; else R.w = res;
    }
    if (LAST) {
        *(f4v*)(outp + y * 768 + x0) = R;
    } else if (interior) {
        *(f4v*)(Y + y * W2 + x0) = R;
    } else {
        // zero outside the image: next iteration zero-pads at the boundary
        const bool rowin = ((unsigned)(gy0 + y) < 768u);
        R.x = (rowin && (unsigned)(gx0 + x0 + 0) < 768u) ? R.x : 0.0f;
        R.y = (rowin && (unsigned)(gx0 + x0 + 1) < 768u) ? R.y : 0.0f;
        R.z = (rowin && (unsigned)(gx0 + x0 + 2) < 768u) ? R.z : 0.0f;
        R.w = (rowin && (unsigned)(gx0 + x0 + 3) < 768u) ? R.w : 0.0f;
        *(f4v*)(Y + y * W2 + x0) = R;
    }
}

// One SWF iteration, balanced piece mapping. X: (H2+4) x (W2+4) LDS tile
// (pitch W2+4, zero-pad). A "run" = (strip, parity): STRIPS 4-px columns x 2
// parities = 2*STRIPS runs of H2/2 parity-rows each. Each run is cut into
// pieces of 2 or 3 consecutive same-parity rows; piece counts are chosen so
// the step has EXACTLY 256 pieces (all threads busy, no idle chains, no
// over-scheduled rows). Pieces are enumerated len-2-first / run-fastest:
// waves are length-pure except one boundary wave, and consecutive lanes read
// consecutive strips. First row of a piece is FULL (fresh U/NW/NE, bitwise ==
// ring values); rows 2-3 reuse the previous row's D/SW/SE via the identities.
template<int H2, int W2, bool LAST>
__device__ __forceinline__ void stepv(const float* __restrict__ X,
                                      float* __restrict__ Y,
                                      float* __restrict__ outp,
                                      int gy0, int gx0, int tid) {
    constexpr int PW     = W2 + 4;
    constexpr int STRIPS = W2 / 4;                    // 18 / 17 / 16
    static_assert(H2 == 40 || H2 == 36 || H2 == 32, "piece tables");

    const bool interior = (gy0 >= 0) && (gx0 >= 0) &&
                          (gy0 + H2 <= 768) && (gx0 + W2 <= 768);

    int run, start, len;                  // start in parity-row units
    if constexpr (H2 == 40) {
        // 36 runs x 20 parity-rows = 720 rows, 256 pieces (48 len2, 208 len3).
        // A-runs 0..3:  len2 @ {0,2,4,6},     len3 @ {8,11,14,17}
        // B-runs 4..35: len2 @ {0},           len3 @ {2,5,8,11,14,17}
        if (tid < 16)      { run = tid & 3;              start = 2 * (tid >> 2);        len = 2; }
        else if (tid < 48) { run = 4 + ((tid - 16) & 31); start = 0;                    len = 2; }
        else if (tid < 64) { int u = tid - 48; run = u & 3;        start = 8 + 3 * (u >> 2); len = 3; }
        else               { int u = tid - 64; run = 4 + (u & 31); start = 2 + 3 * (u >> 5); len = 3; }
    } else if constexpr (H2 == 36) {
        // 34 runs x 18 = 612 rows, 256 pieces (156 len2, 100 len3).
        // A-runs 0..17:  len2 @ {0,2,4,6,8,10}, len3 @ {12,15}
        // B-runs 18..33: len2 @ {0,2,4},        len3 @ {6,9,12,15}
        if (tid < 108)      { run = tid % 18;                      start = 2 * (tid / 18);     len = 2; }
        else if (tid < 156) { int u = tid - 108; run = 18 + (u & 15); start = 2 * (u >> 4);    len = 2; }
        else if (tid < 192) { int u = tid - 156; run = u % 18;        start = 12 + 3 * (u / 18); len = 3; }
        else                { int u = tid - 192; run = 18 + (u & 15); start = 6 + 3 * (u >> 4);  len = 3; }
    } else {
        // 32 runs x 16 = 512 rows, 256 pieces, all len2 (== prior iter3 map).
        run = tid & 31; start = 2 * (tid >> 5); len = 2;
    }

    const int par   = (run >= STRIPS) ? 1 : 0;
    const int strip = run - par * STRIPS;
    const int x0    = strip * 4;
    const int y     = par + 2 * start;

    const float* rp = X + y * PW + x0;
    float Rv[6], D0[4], S0[4], E0[4], U0[4], N0[4], M0[4], ctr[4];
    // row 0: full (fresh U/NW/NE)
    swf_row<PW, true >(rp, Rv, D0, S0, E0, U0, N0, M0, ctr);
    emit_store<W2, LAST>(Rv, U0, N0, M0, D0, S0, E0, ctr,
                         Y, outp, y, x0, gy0, gx0, interior);
    // row 1 (y+2): U/NW/NE come from row 0's D/SW/SE (bitwise identities)
    float D1[4], S1[4], E1[4];
    swf_row<PW, false>(rp + 2 * PW, Rv, D1, S1, E1, U0, N0, M0, ctr);
    emit_store<W2, LAST>(Rv, D0, S0, E0, D1, S1, E1, ctr,
                         Y, outp, y + 2, x0, gy0, gx0, interior);
    // row 2 (y+4), only for len-3 pieces; rotates back into D0/S0/E0
    if (len == 3) {
        swf_row<PW, false>(rp + 4 * PW, Rv, D0, S0, E0, U0, N0, M0, ctr);
        emit_store<W2, LAST>(Rv, D1, S1, E1, D0, S0, E0, ctr,
                             Y, outp, y + 4, x0, gy0, gx0, interior);
    }
    __syncthreads();
}

// LDS: A = 44x76 fp32 (iter1 input; reused as iter2 output 36x68) = 13376 B,
//      B = 40x72 fp32 (iter1 output = iter2 input) = 11520 B. Total 24896 B
//      -> 6 blocks/CU (24 waves/CU). launch_bounds(256,6) matches the
//      LDS-imposed occupancy and leaves the register cap at ~85/wave.
__global__ __launch_bounds__(256, 6) void swf_fused(const float* __restrict__ in,
                                                    float* __restrict__ out) {
    __shared__ __align__(16) float A[44 * 76];
    __shared__ __align__(16) float B[40 * 72];

    const int tid = threadIdx.x;
    const int tx0 = blockIdx.x * 64;
    const int ty0 = blockIdx.y * 32;
    const long long base = (long long)blockIdx.z * (768 * 768);
    const float* inp = in + base;

    // load tile rows ty0-6..ty0+37, cols tx0-6..tx0+69, zero-padded.
    // float2 granularity: global col tx0-6 is even -> 8B aligned.
    for (int i = tid; i < 44 * 38; i += 256) {
        const int ly  = i / 38;
        const int lx2 = i - ly * 38;
        const int gy  = ty0 + ly - 6;
        const int gx  = tx0 + lx2 * 2 - 6;
        f2v v = {0.0f, 0.0f};
        if ((unsigned)gy < 768u) {
            const float* g = inp + gy * 768 + gx;
            if ((unsigned)gx < 767u) {            // both lanes inside
                v = *(const f2v*)g;
            } else {                               // x-edge: per-lane
                if ((unsigned)gx < 768u)       v.x = g[0];
                if ((unsigned)(gx + 1) < 768u) v.y = g[1];
            }
        }
        *(f2v*)(A + ly * 76 + lx2 * 2) = v;
    }
    __syncthreads();

    stepv<40, 72, false>(A, B, nullptr, ty0 - 4, tx0 - 4, tid);  // iter1: A->B
    stepv<36, 68, false>(B, A, nullptr, ty0 - 2, tx0 - 2, tid);  // iter2: B->A
    stepv<32, 64, true >(A, nullptr,                              // iter3: A->out
                         out + base + (long long)ty0 * 768 + tx0, ty0, tx0, tid);
}

extern "C" void kernel_launch(void* const* d_in, const int* in_sizes, int n_in,
                              void* d_out, int out_size, void* d_ws, size_t ws_size,
                              hipStream_t stream) {
    const float* x = (const float*)d_in[0];
    float* out = (float*)d_out;

    dim3 grid(768 / 64, 768 / 32, 24);   // 12 x 24 x 24 = 6912 blocks
    dim3 block(256);
    swf_fused<<<grid, block, 0, stream>>>(x, out);
}

// Round 8
// 183.426 us; speedup vs baseline: 1.2548x; 1.0078x over previous
//
#include <hip/hip_runtime.h>
#include <math.h>

// Side-window filter, 3 iterations fused, FP32, bit-exact vs the np reference
// (verified absmax==0.0): each directional conv is a sequential fp32 FMA chain
// over taps in row-major (ky,kx) order, weights fp32(1/15), fp32(1/9),
// fp32(fp32(1/9)/9). Zero-padded taps are exact no-ops; chain heads are muls
// (== fmaf onto +0, verified bit-exact in round 4). Intermediates fp32;
// out-of-image intermediate pixels zeroed (next iteration zero-pads).
//
// Round 14: rolling tap-row register window. Wave-level accounting showed
// true VALU utilization ~45% (the 81% VALUBusy reading is the gfx94x-fallback
// formula counting 4 cyc/wave64-instr on CDNA4's 2-cyc SIMD-32) -> the kernel
// is latency-stall-bound, dominated by the 10 dependent ds_read_b128 heading
// every row-body. Fix: consecutive piece rows (y, y+2, y+4) share 3 of 5 tap
// rows; keep 7 tap rows in named registers (t0..t6), compute row y from
// t0-t4, row y+2 from t2-t6 (3/5 taps resident -> ~132 FMAs issue with no
// LDS wait, covering t5/t6 latency), row y+4 from t4-t6 + reloaded t0,t1.
// ds_read wave-instrs -30..40%; launch_bounds(256,5) raises the register cap
// to ~102 for the ~95 live floats (20 waves/CU ~= the 18.5 measured resident).
// Chains, argmin tree, identities: byte-identical (register-reuse only).
//
// Round 13 (kept): balanced piece mapping — each step's H2 x STRIPS row-tasks
// cut into EXACTLY 256 pieces of 2-3 same-parity consecutive rows, len-2-first
// / run-fastest ordering (all threads busy, waves length-pure except one).
// Round 11 (kept): exact-sharing. Four BITWISE identities:
//   L[x,y] == R[x-2,y]   (w15, 5 rows x 3 cols)
//   U[x,y] == D[x,y-2]   (w15, 3 rows x 5 cols)
//   NW[x,y]== SW[x,y-2]  (w9,  3x3, cols x-2..x)
//   NE[x,y]== SE[x,y-2]  (w81, same support as NW/SW — the reference bug)
//
// Direction supports (with the reference's normalization bug):
//   d0 L  = rows[-2..2] x cols[-2..0] * (1/15)
//   d1 R  = rows[-2..2] x cols[0..2]  * (1/15)
//   d2 U  = rows[-2..0] x cols[-2..2] * (1/15)
//   d3 D  = rows[0..2]  x cols[-2..2] * (1/15)
//   d4 NW = rows[-2..0] x cols[-2..0] * (1/9)
//   d5 NE = NW support * (1/81)
//   d6 SW = rows[0..2]  x cols[-2..0] * (1/9)
//   d7 SE = SW support * (1/81)

typedef float f4v __attribute__((ext_vector_type(4)));
typedef float f2v __attribute__((ext_vector_type(2), aligned(8)));

struct Row8 { f4v lo, hi; };

__device__ __forceinline__ void ldrow(Row8& t, const float* p) {
    t.lo = *(const f4v*)p;          // 16B-aligned
    t.hi = *(const f4v*)(p + 4);
}

// Process one tap row (compile-time r = 0..4) for a 4-px output row.
// Chain order per accumulator: tap rows ascending, cols ascending within row
// — the verified bit-exact chain. Do not reorder within a chain.
template<int r, bool FULL>
__device__ __forceinline__ void tap_row(const Row8& t,
        float* Rv, float* Dv, float* SWv, float* SEv,
        float* Uv, float* NWv, float* NEv, float* ctr) {
    const float w15 = 1.0f / 15.0f;
    const float w9  = 1.0f / 9.0f;
    const float w81 = (1.0f / 9.0f) / 9.0f;

    float w[8] = {t.lo.x, t.lo.y, t.lo.z, t.lo.w,
                  t.hi.x, t.hi.y, t.hi.z, t.hi.w};

    // R chains at 6 positions; w[q] = tap col x0-2+q
    #pragma unroll
    for (int q = 0; q < 6; q++) {
        float a = (r == 0) ? (w15 * w[q]) : fmaf(w15, w[q], Rv[q]);
        a = fmaf(w15, w[q + 1], a);
        a = fmaf(w15, w[q + 2], a);
        Rv[q] = a;
    }

    #pragma unroll
    for (int j = 0; j < 4; j++) {
        if (FULL && r < 3) {           // U, NW, NE (tap rows y-2..y)
            float u = (r == 0) ? (w15 * w[j]) : fmaf(w15, w[j], Uv[j]);
            u = fmaf(w15, w[j + 1], u);
            u = fmaf(w15, w[j + 2], u);
            u = fmaf(w15, w[j + 3], u);
            u = fmaf(w15, w[j + 4], u);
            Uv[j] = u;
            float nw = (r == 0) ? (w9 * w[j]) : fmaf(w9, w[j], NWv[j]);
            nw = fmaf(w9, w[j + 1], nw);
            nw = fmaf(w9, w[j + 2], nw);
            NWv[j] = nw;
            float ne = (r == 0) ? (w81 * w[j]) : fmaf(w81, w[j], NEv[j]);
            ne = fmaf(w81, w[j + 1], ne);
            ne = fmaf(w81, w[j + 2], ne);
            NEv[j] = ne;
        }
        if (r >= 2) {                  // D, SW, SE (tap rows y..y+2)
            float d = (r == 2) ? (w15 * w[j]) : fmaf(w15, w[j], Dv[j]);
            d = fmaf(w15, w[j + 1], d);
            d = fmaf(w15, w[j + 2], d);
            d = fmaf(w15, w[j + 3], d);
            d = fmaf(w15, w[j + 4], d);
            Dv[j] = d;
            float sw = (r == 2) ? (w9 * w[j]) : fmaf(w9, w[j], SWv[j]);
            sw = fmaf(w9, w[j + 1], sw);
            sw = fmaf(w9, w[j + 2], sw);
            SWv[j] = sw;
            float se = (r == 2) ? (w81 * w[j]) : fmaf(w81, w[j], SEv[j]);
            se = fmaf(w81, w[j + 1], se);
            se = fmaf(w81, w[j + 2], se);
            SEv[j] = se;
            if (r == 2) ctr[j] = w[j + 2];
        }
    }
}

// One output row from 5 resident tap rows.
template<bool FULL>
__device__ __forceinline__ void swf_row_regs(
        const Row8& t0, const Row8& t1, const Row8& t2,
        const Row8& t3, const Row8& t4,
        float* Rv, float* Dv, float* SWv, float* SEv,
        float* Uv, float* NWv, float* NEv, float* ctr) {
    tap_row<0, FULL>(t0, Rv, Dv, SWv, SEv, Uv, NWv, NEv, ctr);
    tap_row<1, FULL>(t1, Rv, Dv, SWv, SEv, Uv, NWv, NEv, ctr);
    tap_row<2, FULL>(t2, Rv, Dv, SWv, SEv, Uv, NWv, NEv, ctr);
    tap_row<3, FULL>(t3, Rv, Dv, SWv, SEv, Uv, NWv, NEv, ctr);
    tap_row<4, FULL>(t4, Rv, Dv, SWv, SEv, Uv, NWv, NEv, ctr);
}

// argmin tournament + store for one 4-px row. e-order (L,R,U,D,NW,NE,SW,SE)
// and strict-< tree identical to the verified kernel (lowest index on ties).
template<int W2, bool LAST>
__device__ __forceinline__ void emit_store(const float* Rv,
        const float* Ua, const float* NWa, const float* NEa,
        const float* Dn, const float* SWn, const float* SEn, const float* ctr,
        float* __restrict__ Y, float* __restrict__ outp,
        int y, int x0, int gy0, int gx0, bool interior) {
    f4v R;
    #pragma unroll
    for (int j = 0; j < 4; j++) {
        const float c  = ctr[j];
        const float e0 = Rv[j]     - c;   // L  == R[x-2] (same row)
        const float e1 = Rv[j + 2] - c;   // R
        const float e2 = Ua[j]     - c;   // U  (fresh or D[y-2])
        const float e3 = Dn[j]     - c;   // D
        const float e4 = NWa[j]    - c;   // NW (fresh or SW[y-2])
        const float e5 = NEa[j]    - c;   // NE (fresh or SE[y-2])
        const float e6 = SWn[j]    - c;   // SW
        const float e7 = SEn[j]    - c;   // SE
        float m01 = (fabsf(e1) < fabsf(e0)) ? e1 : e0;
        float m23 = (fabsf(e3) < fabsf(e2)) ? e3 : e2;
        float m45 = (fabsf(e5) < fabsf(e4)) ? e5 : e4;
        float m67 = (fabsf(e7) < fabsf(e6)) ? e7 : e6;
        float mA  = (fabsf(m23) < fabsf(m01)) ? m23 : m01;
        float mB  = (fabsf(m67) < fabsf(m45)) ? m67 : m45;
        float bd  = (fabsf(mB)  < fabsf(mA))  ? mB  : mA;
        const float res = c + bd;
        if (j == 0) R.x = res; else if (j == 1) R.y = res;
        else if (j == 2) R.z = res; else R.w = res;
    }
    if (LAST) {
        *(f4v*)(outp + y * 768 + x0) = R;
    } else if (interior) {
        *(f4v*)(Y + y * W2 + x0) = R;
    } else {
        // zero outside the image: next iteration zero-pads at the boundary
        const bool rowin = ((unsigned)(gy0 + y) < 768u);
        R.x = (rowin && (unsigned)(gx0 + x0 + 0) < 768u) ? R.x : 0.0f;
        R.y = (rowin && (unsigned)(gx0 + x0 + 1) < 768u) ? R.y : 0.0f;
        R.z = (rowin && (unsigned)(gx0 + x0 + 2) < 768u) ? R.z : 0.0f;
        R.w = (rowin && (unsigned)(gx0 + x0 + 3) < 768u) ? R.w : 0.0f;
        *(f4v*)(Y + y * W2 + x0) = R;
    }
}

// One SWF iteration, balanced piece mapping + rolling tap window.
// X: (H2+4) x (W2+4) LDS tile (pitch W2+4, zero-pad). A "run" = (strip,
// parity); each run is cut into pieces of 2-3 same-parity consecutive rows;
// exactly 256 pieces per step. First row of a piece is FULL (fresh U/NW/NE,
// bitwise == ring values); rows 2-3 reuse the previous row's D/SW/SE.
template<int H2, int W2, bool LAST>
__device__ __forceinline__ void stepv(const float* __restrict__ X,
                                      float* __restrict__ Y,
                                      float* __restrict__ outp,
                                      int gy0, int gx0, int tid) {
    constexpr int PW     = W2 + 4;
    constexpr int STRIPS = W2 / 4;                    // 18 / 17 / 16
    static_assert(H2 == 40 || H2 == 36 || H2 == 32, "piece tables");

    const bool interior = (gy0 >= 0) && (gx0 >= 0) &&
                          (gy0 + H2 <= 768) && (gx0 + W2 <= 768);

    int run, start, len;                  // start in parity-row units
    if constexpr (H2 == 40) {
        // 36 runs x 20 parity-rows = 720 rows, 256 pieces (48 len2, 208 len3).
        if (tid < 16)      { run = tid & 3;              start = 2 * (tid >> 2);        len = 2; }
        else if (tid < 48) { run = 4 + ((tid - 16) & 31); start = 0;                    len = 2; }
        else if (tid < 64) { int u = tid - 48; run = u & 3;        start = 8 + 3 * (u >> 2); len = 3; }
        else               { int u = tid - 64; run = 4 + (u & 31); start = 2 + 3 * (u >> 5); len = 3; }
    } else if constexpr (H2 == 36) {
        // 34 runs x 18 = 612 rows, 256 pieces (156 len2, 100 len3).
        if (tid < 108)      { run = tid % 18;                      start = 2 * (tid / 18);     len = 2; }
        else if (tid < 156) { int u = tid - 108; run = 18 + (u & 15); start = 2 * (u >> 4);    len = 2; }
        else if (tid < 192) { int u = tid - 156; run = u % 18;        start = 12 + 3 * (u / 18); len = 3; }
        else                { int u = tid - 192; run = 18 + (u & 15); start = 6 + 3 * (u >> 4);  len = 3; }
    } else {
        // 32 runs x 16 = 512 rows, 256 pieces, all len2.
        run = tid & 31; start = 2 * (tid >> 5); len = 2;
    }

    const int par   = (run >= STRIPS) ? 1 : 0;
    const int strip = run - par * STRIPS;
    const int x0    = strip * 4;
    const int y     = par + 2 * start;

    const float* rp = X + y * PW + x0;

    // rolling tap window: rows y..y+6 (t5,t6 prefetched ahead of row-y math)
    Row8 t0, t1, t2, t3, t4, t5, t6;
    ldrow(t0, rp);
    ldrow(t1, rp + PW);
    ldrow(t2, rp + 2 * PW);
    ldrow(t3, rp + 3 * PW);
    ldrow(t4, rp + 4 * PW);
    ldrow(t5, rp + 5 * PW);
    ldrow(t6, rp + 6 * PW);

    float Rv[6], D0[4], S0[4], E0[4], U0[4], N0[4], M0[4], ctr[4];
    // row y: full (fresh U/NW/NE)
    swf_row_regs<true >(t0, t1, t2, t3, t4, Rv, D0, S0, E0, U0, N0, M0, ctr);
    emit_store<W2, LAST>(Rv, U0, N0, M0, D0, S0, E0, ctr,
                         Y, outp, y, x0, gy0, gx0, interior);
    // row y+2: taps t2..t6 (3/5 already resident); U/NW/NE = row y's D/SW/SE
    float D1[4], S1[4], E1[4];
    swf_row_regs<false>(t2, t3, t4, t5, t6, Rv, D1, S1, E1, U0, N0, M0, ctr);
    emit_store<W2, LAST>(Rv, D0, S0, E0, D1, S1, E1, ctr,
                         Y, outp, y + 2, x0, gy0, gx0, interior);
    // row y+4 (len-3 pieces): taps t4,t5,t6 + reloaded t0,t1 (rows y+7,y+8)
    if (len == 3) {
        ldrow(t0, rp + 7 * PW);
        ldrow(t1, rp + 8 * PW);
        swf_row_regs<false>(t4, t5, t6, t0, t1, Rv, D0, S0, E0, U0, N0, M0, ctr);
        emit_store<W2, LAST>(Rv, D1, S1, E1, D0, S0, E0, ctr,
                             Y, outp, y + 4, x0, gy0, gx0, interior);
    }
    __syncthreads();
}

// LDS: A = 44x76 fp32 (iter1 input; reused as iter2 output 36x68) = 13376 B,
//      B = 40x72 fp32 (iter1 output = iter2 input) = 11520 B. Total 24896 B.
// launch_bounds(256,5): register cap ~102 for the ~95 live floats of the
// rolling window (20 waves/CU ~= the 18.5 measured resident at (256,6)).
__global__ __launch_bounds__(256, 5) void swf_fused(const float* __restrict__ in,
                                                    float* __restrict__ out) {
    __shared__ __align__(16) float A[44 * 76];
    __shared__ __align__(16) float B[40 * 72];

    const int tid = threadIdx.x;
    const int tx0 = blockIdx.x * 64;
    const int ty0 = blockIdx.y * 32;
    const long long base = (long long)blockIdx.z * (768 * 768);
    const float* inp = in + base;

    // load tile rows ty0-6..ty0+37, cols tx0-6..tx0+69, zero-padded.
    // float2 granularity: global col tx0-6 is even -> 8B aligned.
    for (int i = tid; i < 44 * 38; i += 256) {
        const int ly  = i / 38;
        const int lx2 = i - ly * 38;
        const int gy  = ty0 + ly - 6;
        const int gx  = tx0 + lx2 * 2 - 6;
        f2v v = {0.0f, 0.0f};
        if ((unsigned)gy < 768u) {
            const float* g = inp + gy * 768 + gx;
            if ((unsigned)gx < 767u) {            // both lanes inside
                v = *(const f2v*)g;
            } else {                               // x-edge: per-lane
                if ((unsigned)gx < 768u)       v.x = g[0];
                if ((unsigned)(gx + 1) < 768u) v.y = g[1];
            }
        }
        *(f2v*)(A + ly * 76 + lx2 * 2) = v;
    }
    __syncthreads();

    stepv<40, 72, false>(A, B, nullptr, ty0 - 4, tx0 - 4, tid);  // iter1: A->B
    stepv<36, 68, false>(B, A, nullptr, ty0 - 2, tx0 - 2, tid);  // iter2: B->A
    stepv<32, 64, true >(A, nullptr,                              // iter3: A->out
                         out + base + (long long)ty0 * 768 + tx0, ty0, tx0, tid);
}

extern "C" void kernel_launch(void* const* d_in, const int* in_sizes, int n_in,
                              void* d_out, int out_size, void* d_ws, size_t ws_size,
                              hipStream_t stream) {
    const float* x = (const float*)d_in[0];
    float* out = (float*)d_out;

    dim3 grid(768 / 64, 768 / 32, 24);   // 12 x 24 x 24 = 6912 blocks
    dim3 block(256);
    swf_fused<<<grid, block, 0, stream>>>(x, out);
}